// Round 1
// baseline (335.659 us; speedup 1.0000x reference)
//
#include <hip/hip_runtime.h>
#include <cmath>

#define NB 64
#define NCC 256
#define NH 36
#define NW 36
#define NHW 1296
#define NK 16
#define NI 8
#define SC (1.0f/16.0f)
#define MT 216

__device__ __forceinline__ float hatc(float t){
  t = fminf(fmaxf(t, -1.0f), 1.0f);
  float a = 1.0f + t, bq = 1.0f - t;
  return (t < 0.0f) ? 0.5f*a*a : 1.0f - 0.5f*bq*bq;
}

// ---- K1a: per-box axis weights + inv area -------------------------------
__global__ void k_weights(const float* __restrict__ bb1,
                          float* __restrict__ wY, float* __restrict__ wX,
                          float* __restrict__ inv_area){
  int b = blockIdx.x;
  int t = threadIdx.x;
  float bx = bb1[b*4+0], by = bb1[b*4+1], bwv = bb1[b*4+2], bhv = bb1[b*4+3];
  float x1 = bx*SC, y1 = by*SC;
  float x2 = (bx+bwv)*SC, y2 = (by+bhv)*SC;
  float binw = (x2-x1)*0.25f, binh = (y2-y1)*0.25f;
  if (t < 144){
    int p = t / 36, i = t - p*36;
    float fi = (float)i;
    float lo = y1 + p*binh, hi = lo + binh;
    wY[b*144+t] = hatc(hi - fi) - hatc(lo - fi);
    lo = x1 + p*binw; hi = lo + binw;
    wX[b*144+t] = hatc(hi - fi) - hatc(lo - fi);
  }
  if (t == 0){
    float area = binw*binh;
    inv_area[b] = (area > 0.0f) ? 1.0f/fmaxf(area,1e-12f) : 0.0f;
  }
}

// ---- K1b: PrRoI pooling -> kflat[b][c][16] ------------------------------
__global__ __launch_bounds__(256) void k_prpool(const float* __restrict__ feat1,
    const float* __restrict__ wY, const float* __restrict__ wX,
    const float* __restrict__ inv_area, float* __restrict__ kflat){
  int bc = blockIdx.x;           // b*256 + c
  int b = bc >> 8;
  int t = threadIdx.x;
  __shared__ float sw[288];      // [0,144)=wY rows p, [144,288)=wX
  __shared__ float red[4][16];
  if (t < 144){ sw[t] = wY[b*144+t]; sw[144+t] = wX[b*144+t]; }
  __syncthreads();
  float acc[16];
  #pragma unroll
  for (int k=0;k<16;k++) acc[k]=0.0f;
  const float* fp = feat1 + (size_t)bc*NHW;
  for (int idx=t; idx<NHW; idx+=256){
    int h = idx/36;
    int w = idx - h*36;
    float v = fp[idx];
    float v0 = v*sw[h], v1 = v*sw[36+h], v2 = v*sw[72+h], v3 = v*sw[108+h];
    float wx0 = sw[144+w], wx1 = sw[180+w], wx2 = sw[216+w], wx3 = sw[252+w];
    acc[0] += v0*wx0;  acc[1] += v0*wx1;  acc[2] += v0*wx2;  acc[3] += v0*wx3;
    acc[4] += v1*wx0;  acc[5] += v1*wx1;  acc[6] += v1*wx2;  acc[7] += v1*wx3;
    acc[8] += v2*wx0;  acc[9] += v2*wx1;  acc[10]+= v2*wx2;  acc[11]+= v2*wx3;
    acc[12]+= v3*wx0;  acc[13]+= v3*wx1;  acc[14]+= v3*wx2;  acc[15]+= v3*wx3;
  }
  #pragma unroll
  for (int k=0;k<16;k++){
    float a = acc[k];
    #pragma unroll
    for (int off=32; off>0; off>>=1) a += __shfl_down(a, off);
    acc[k] = a;
  }
  int wv = t >> 6;
  if ((t & 63) == 0){
    #pragma unroll
    for (int k=0;k<16;k++) red[wv][k] = acc[k];
  }
  __syncthreads();
  if (t < 16){
    float s = red[0][t] + red[1][t] + red[2][t] + red[3][t];
    kflat[(size_t)bc*16 + t] = s * inv_area[b];
  }
}

// ---- K2: pixel correlation corr[b][k][hw] + per-block channel sums ------
__global__ __launch_bounds__(256) void k_corr(const float* __restrict__ feat2,
    const float* __restrict__ kflat, float* __restrict__ corr,
    float* __restrict__ partial){
  int blk = blockIdx.x;
  int b = blk / 6;
  int ch = blk - b*6;
  int t = threadIdx.x;
  __shared__ float kl[4096];
  __shared__ float red[4][16];
  for (int i=t; i<4096; i+=256) kl[i] = kflat[(size_t)b*4096 + i];
  __syncthreads();
  int pix = ch*256 + t;
  bool act = pix < NHW;
  float acc[16];
  #pragma unroll
  for (int k=0;k<16;k++) acc[k]=0.0f;
  if (act){
    const float* f2 = feat2 + (size_t)b*NCC*NHW + pix;
    for (int c=0;c<NCC;c++){
      float v = f2[(size_t)c*NHW];
      const float4* k4 = (const float4*)(&kl[c*16]);
      float4 ka = k4[0], kb = k4[1], kc = k4[2], kd = k4[3];
      acc[0]+=v*ka.x; acc[1]+=v*ka.y; acc[2]+=v*ka.z; acc[3]+=v*ka.w;
      acc[4]+=v*kb.x; acc[5]+=v*kb.y; acc[6]+=v*kb.z; acc[7]+=v*kb.w;
      acc[8]+=v*kc.x; acc[9]+=v*kc.y; acc[10]+=v*kc.z; acc[11]+=v*kc.w;
      acc[12]+=v*kd.x; acc[13]+=v*kd.y; acc[14]+=v*kd.z; acc[15]+=v*kd.w;
    }
    float* cp = corr + (size_t)b*NK*NHW + pix;
    #pragma unroll
    for (int k=0;k<16;k++) cp[(size_t)k*NHW] = acc[k];
  }
  #pragma unroll
  for (int k=0;k<16;k++){
    float a = acc[k];
    #pragma unroll
    for (int off=32; off>0; off>>=1) a += __shfl_down(a, off);
    acc[k] = a;
  }
  int wv = t >> 6;
  if ((t & 63)==0){
    #pragma unroll
    for (int k=0;k<16;k++) red[wv][k]=acc[k];
  }
  __syncthreads();
  if (t < 16)
    partial[(size_t)blk*16 + t] = red[0][t]+red[1][t]+red[2][t]+red[3][t];
}

// ---- K3: SE gate --------------------------------------------------------
__global__ void k_se(const float* __restrict__ partial,
                     const float* __restrict__ w1, const float* __restrict__ w2,
                     float* __restrict__ sscale){
  int b = threadIdx.x;
  if (b >= NB) return;
  float s[16];
  #pragma unroll
  for (int k=0;k<16;k++){
    float a = 0.f;
    for (int c2=0; c2<6; c2++) a += partial[(b*6+c2)*16 + k];
    s[k] = a * (1.0f/1296.0f);
  }
  float r[4];
  #pragma unroll
  for (int j=0;j<4;j++){
    float a=0.f;
    #pragma unroll
    for (int k=0;k<16;k++) a += s[k]*w1[j*16+k];
    r[j] = fmaxf(a, 0.f);
  }
  #pragma unroll
  for (int k=0;k<16;k++){
    float a=0.f;
    #pragma unroll
    for (int j=0;j<4;j++) a += r[j]*w2[k*4+j];
    sscale[b*16+k] = 1.0f/(1.0f+__expf(-a));
  }
}

// ---- K4: theta/phi/g projections ---------------------------------------
__global__ __launch_bounds__(256) void k_tpg(const float* __restrict__ corr,
    const float* __restrict__ sscale,
    const float* __restrict__ tw, const float* __restrict__ tb,
    const float* __restrict__ pw, const float* __restrict__ pb,
    const float* __restrict__ gw, const float* __restrict__ gb,
    float* __restrict__ theta, float* __restrict__ phi, float* __restrict__ g){
  int blk = blockIdx.x;
  int b = blk/6;
  int ch = blk - b*6;
  int t = threadIdx.x;
  __shared__ float Wt[128], Wp[128], Wg[128], Bz[24], Ss[16];
  if (t < 128){ Wt[t]=tw[t]; Wp[t]=pw[t]; Wg[t]=gw[t]; }
  if (t < 8){ Bz[t]=tb[t]; Bz[8+t]=pb[t]; Bz[16+t]=gb[t]; }
  if (t < 16) Ss[t] = sscale[b*16+t];
  __syncthreads();
  int n = ch*256 + t;
  if (n >= NHW) return;
  float x[16];
  const float* cp = corr + (size_t)b*NK*NHW + n;
  #pragma unroll
  for (int c=0;c<16;c++) x[c] = cp[(size_t)c*NHW] * Ss[c];
  float th[8], ph[8], gg[8];
  #pragma unroll
  for (int o=0;o<8;o++){
    float a=Bz[o], p2=Bz[8+o], gq=Bz[16+o];
    #pragma unroll
    for (int c=0;c<16;c++){
      a  += Wt[o*16+c]*x[c];
      p2 += Wp[o*16+c]*x[c];
      gq += Wg[o*16+c]*x[c];
    }
    th[o]=a; ph[o]=p2; gg[o]=gq;
  }
  size_t base = ((size_t)b*NHW + n)*8;
  #pragma unroll
  for (int o=0;o<8;o++){ theta[base+o]=th[o]; phi[base+o]=ph[o]; g[base+o]=gg[o]; }
}

// ---- K5: flash attention over N=1296, d=8, + W-proj + residual ----------
__global__ __launch_bounds__(64) void k_attn(const float* __restrict__ theta,
    const float* __restrict__ phi, const float* __restrict__ g,
    const float* __restrict__ corr, const float* __restrict__ sscale,
    const float* __restrict__ Ww, const float* __restrict__ Wb,
    float* __restrict__ out){
  int blk = blockIdx.x;
  int b = blk / 21;
  int ch = blk - b*21;
  int lane = threadIdx.x;
  int n = ch*64 + lane;
  bool act = n < NHW;
  __shared__ float sphi[MT*8];
  __shared__ float sg[MT*8];
  float th[8];
  if (act){
    const float* tp = theta + ((size_t)b*NHW + n)*8;
    #pragma unroll
    for (int o=0;o<8;o++) th[o]=tp[o];
  } else {
    #pragma unroll
    for (int o=0;o<8;o++) th[o]=0.0f;
  }
  float mr = -INFINITY, l = 0.0f;
  float y[8];
  #pragma unroll
  for (int o=0;o<8;o++) y[o]=0.0f;

  for (int t0=0; t0<NHW; t0+=MT){
    __syncthreads();
    const float4* pp = (const float4*)(phi + ((size_t)b*NHW + t0)*8);
    const float4* gp = (const float4*)(g   + ((size_t)b*NHW + t0)*8);
    float4* sp4 = (float4*)sphi;
    float4* sg4 = (float4*)sg;
    for (int i=lane; i<MT*2; i+=64){ sp4[i]=pp[i]; sg4[i]=gp[i]; }
    __syncthreads();
    if (act){
      for (int j=0;j<MT;j++){
        const float* pr = &sphi[j*8];
        float s0 = th[0]*pr[0] + th[2]*pr[2];
        float s1 = th[1]*pr[1] + th[3]*pr[3];
        s0 += th[4]*pr[4] + th[6]*pr[6];
        s1 += th[5]*pr[5] + th[7]*pr[7];
        float s = s0 + s1;
        const float* gr = &sg[j*8];
        if (s <= mr){
          float p = __expf(s - mr);
          l += p;
          #pragma unroll
          for (int o=0;o<8;o++) y[o] += p*gr[o];
        } else {
          float cf = __expf(mr - s);
          mr = s;
          l = l*cf + 1.0f;
          #pragma unroll
          for (int o=0;o<8;o++) y[o] = y[o]*cf + gr[o];
        }
      }
    }
  }
  if (act){
    float invl = 1.0f / l;
    #pragma unroll
    for (int o=0;o<8;o++) y[o] *= invl;
    const float* cp = corr + (size_t)b*NK*NHW + n;
    const float* ss = sscale + b*16;
    float* op = out + (size_t)b*NK*NHW + n;
    #pragma unroll
    for (int c2=0;c2<16;c2++){
      float z = Wb[c2];
      #pragma unroll
      for (int o=0;o<8;o++) z += Ww[c2*8+o]*y[o];
      op[(size_t)c2*NHW] = z + cp[(size_t)c2*NHW]*ss[c2];
    }
  }
}

extern "C" void kernel_launch(void* const* d_in, const int* in_sizes, int n_in,
                              void* d_out, int out_size, void* d_ws, size_t ws_size,
                              hipStream_t stream){
  const float* feat1 = (const float*)d_in[0];
  const float* feat2 = (const float*)d_in[1];
  const float* bb1   = (const float*)d_in[2];
  const float* se_w1 = (const float*)d_in[3];
  const float* se_w2 = (const float*)d_in[4];
  const float* tw    = (const float*)d_in[5];
  const float* tb    = (const float*)d_in[6];
  const float* pw    = (const float*)d_in[7];
  const float* pb    = (const float*)d_in[8];
  const float* gw    = (const float*)d_in[9];
  const float* gb    = (const float*)d_in[10];
  const float* Ww    = (const float*)d_in[11];
  const float* Wb    = (const float*)d_in[12];
  float* out = (float*)d_out;

  float* ws = (float*)d_ws;
  float* wY       = ws;                              // 64*144
  float* wX       = wY + 64*144;                     // 64*144
  float* inv_area = wX + 64*144;                     // 64
  float* kflat    = inv_area + 64;                   // 64*256*16
  float* corr     = kflat + 64*256*16;               // 64*16*1296
  float* partial  = corr + (size_t)64*16*1296;       // 64*6*16
  float* sscale   = partial + 64*6*16;               // 64*16
  float* theta    = sscale + 64*16;                  // 64*1296*8
  float* phi      = theta + (size_t)64*1296*8;       // 64*1296*8
  float* g        = phi   + (size_t)64*1296*8;       // 64*1296*8

  hipLaunchKernelGGL(k_weights, dim3(64), dim3(192), 0, stream, bb1, wY, wX, inv_area);
  hipLaunchKernelGGL(k_prpool, dim3(64*256), dim3(256), 0, stream, feat1, wY, wX, inv_area, kflat);
  hipLaunchKernelGGL(k_corr, dim3(64*6), dim3(256), 0, stream, feat2, kflat, corr, partial);
  hipLaunchKernelGGL(k_se, dim3(1), dim3(64), 0, stream, partial, se_w1, se_w2, sscale);
  hipLaunchKernelGGL(k_tpg, dim3(64*6), dim3(256), 0, stream, corr, sscale, tw, tb, pw, pb, gw, gb, theta, phi, g);
  hipLaunchKernelGGL(k_attn, dim3(64*21), dim3(64), 0, stream, theta, phi, g, corr, sscale, Ww, Wb, out);
}